// Round 12
// baseline (16.403 us; speedup 1.0000x reference)
//
#include <hip/hip_runtime.h>
#include <math.h>

#define APAD 28          // padded row stride for 21-wide tiles
#define W1PAD 132        // padded row stride for 128-wide tiles

// ws float layout (acc zeroed by block 44 each launch; poison-safe):
#define WS_ACC1 0
#define WS_ACC2 512
#define WS_ACC3 1024

// Reset-based dataflow sync: all words 0 at module load; finalizer restores
// them to 0 before kernel end (end-of-dispatch release + stream ordering
// publish the resets to the next launch / graph replay).
// Pure forward dataflow -> no barriers, no leader, no arrival slots.
__device__ unsigned g_zr;    // accumulators zeroed (set by block 44)
__device__ unsigned g_d1;    // FC1 producers done (target 21)
__device__ unsigned g_d2;    // FC2 producers done (target 16)
__device__ unsigned g_cnt;   // FC3 producers done (target 8; 8th finalizes)

// Agent-scope relaxed atomics: cache-bypassing ops served at the coherence
// point -> no L2 wb/inv fences needed anywhere. A vmcnt(0) drain (the
// __syncthreads lowering) means RMWs/stores are acked at the coherence point
// = globally visible; counter bumps after the drain publish the stage.
__device__ __forceinline__ float agent_load(const float* p) {
    return __hip_atomic_load(p, __ATOMIC_RELAXED, __HIP_MEMORY_SCOPE_AGENT);
}
__device__ __forceinline__ void agent_store(float* p, float v) {
    __hip_atomic_store(p, v, __ATOMIC_RELAXED, __HIP_MEMORY_SCOPE_AGENT);
}
__device__ __forceinline__ unsigned flag_load(const unsigned* p) {
    return __hip_atomic_load(p, __ATOMIC_RELAXED, __HIP_MEMORY_SCOPE_AGENT);
}
__device__ __forceinline__ void flag_store(unsigned* p, unsigned v) {
    __hip_atomic_store(p, v, __ATOMIC_RELAXED, __HIP_MEMORY_SCOPE_AGENT);
}
__device__ __forceinline__ void flag_bump(unsigned* p, unsigned* out_prev) {
    *out_prev = __hip_atomic_fetch_add(p, 1u, __ATOMIC_RELAXED,
                                       __HIP_MEMORY_SCOPE_AGENT);
}
__device__ __forceinline__ float agent_fadd(float* p, float v) {
    return __hip_atomic_fetch_add(p, v, __ATOMIC_RELAXED, __HIP_MEMORY_SCOPE_AGENT);
}

// Block barrier waiting ONLY on LDS ops (lgkmcnt): global prefetch loads
// stay in flight across it (__syncthreads would drain vmcnt(0)).
__device__ __forceinline__ void lds_barrier() {
    asm volatile("s_waitcnt lgkmcnt(0)\n\ts_barrier" ::: "memory");
}

// Single launch, 45 blocks x 512 threads, pure dataflow pipeline:
//   blocks 0-20 : GCN (P0-P4 full, P5 row b) + FC1 rows [21b,+21) -> g_d1++
//   blocks 21-36: poll g_d1==21 -> FC2 rows [32(b-21),+32)        -> g_d2++
//   blocks 37-44: poll g_d2==16 -> FC3 rows [64(b-37),+64)        -> g_cnt++
//                 (block 44 also zeroes accs at start, sets g_zr;
//                  8th FC3 finisher writes out and resets sync words)
// No grid barriers; every wait is exactly a data dependency. Forward
// progress does not require co-residency.
__global__ __launch_bounds__(512) void fused_kernel(
    const float* __restrict__ state,      // [B,21,128], only batch 0 used
    const int*   __restrict__ edge_index, // [2,128]
    const float* __restrict__ W1,         // [128,21]
    const float* __restrict__ b1,         // [21]
    const float* __restrict__ W2,         // [21,21]
    const float* __restrict__ b2,         // [21]
    const float* __restrict__ Wf1,        // [441,512]
    const float* __restrict__ bf1,        // [512]
    const float* __restrict__ Wf2,        // [512,512]
    const float* __restrict__ bf2,        // [512]
    const float* __restrict__ Wf3,        // [512,256]
    const float* __restrict__ bf3,        // [256]
    float* __restrict__ ws,
    float* __restrict__ out)
{
    const int b = blockIdx.x;
    const int t = threadIdx.x;

    // ================= FC3 role (blocks 37..44) =================
    if (b >= 37) {
        // Block 44: zero accumulators FIRST (before any vm loads are issued),
        // drain, publish g_zr. Zero stores are the only outstanding vm ops.
        if (b == 44) {
            agent_store(&ws[WS_ACC1 + t], 0.0f);
            agent_store(&ws[WS_ACC2 + t], 0.0f);
            if (t < 256) agent_store(&ws[WS_ACC3 + t], 0.0f);
            __syncthreads();                      // drain zeros (vmcnt 0)
            if (t == 0) flag_store(&g_zr, 1u);
        }

        // Prefetch Wf3 rows [64(b-37), +64) + biases (latency hides under
        // the long g_d2 wait).
        const int r0 = 64 * (b - 37);
        float wf3v[64];
        if (t < 256) {
            #pragma unroll
            for (int i = 0; i < 64; ++i)
                wf3v[i] = Wf3[(size_t)(r0 + i) * 256 + t];
        }
        const float rbf2 = (t < 64) ? bf2[r0 + t] : 0.0f;
        const float rbf3 = bf3[t & 255];

        __shared__ float x2s[64];
        __shared__ unsigned sflag;

        if (t == 0) {
            while (flag_load(&g_d2) < 16u) __builtin_amdgcn_s_sleep(1);
        }
        __syncthreads();

        if (t < 64)
            x2s[t] = fmaxf(agent_load(&ws[WS_ACC2 + r0 + t]) + rbf2, 0.0f);
        lds_barrier();
        if (t < 256) {
            float s = 0.0f;
            #pragma unroll
            for (int j = 0; j < 64; ++j) s += x2s[j] * wf3v[j];
            agent_fadd(&ws[WS_ACC3 + t], s);
        }

        __syncthreads();                          // drain FC3 adds
        if (t == 0) {
            unsigned prev; flag_bump(&g_cnt, &prev);
            sflag = (prev == 7u) ? 1u : 0u;
        }
        __syncthreads();
        if (sflag) {
            if (t < 256) {
                float a = agent_load(&ws[WS_ACC3 + t]) + rbf3;
                out[t] = fmaxf(a, 0.0f);
            }
            // Reset sync words for the next launch (all uses in this launch
            // happen-before the 8th g_cnt bump).
            if (t == 256) flag_store(&g_zr, 0u);
            if (t == 257) flag_store(&g_d1, 0u);
            if (t == 258) flag_store(&g_d2, 0u);
            if (t == 259) flag_store(&g_cnt, 0u);
        }
        return;
    }

    // ================= FC2 role (blocks 21..36) =================
    if (b >= 21) {
        const int r0 = 32 * (b - 21);
        float wf2v[32];
        #pragma unroll
        for (int i = 0; i < 32; ++i)
            wf2v[i] = Wf2[(size_t)(r0 + i) * 512 + t];
        const float rbf1 = (t < 32) ? bf1[r0 + t] : 0.0f;

        __shared__ float x1s[32];

        if (t == 0) {
            while (flag_load(&g_d1) < 21u) __builtin_amdgcn_s_sleep(1);
        }
        __syncthreads();

        if (t < 32)
            x1s[t] = fmaxf(agent_load(&ws[WS_ACC1 + r0 + t]) + rbf1, 0.0f);
        lds_barrier();
        {
            float s = 0.0f;
            #pragma unroll
            for (int j = 0; j < 32; ++j) s += x1s[j] * wf2v[j];
            agent_fadd(&ws[WS_ACC2 + t], s);
        }

        __syncthreads();                          // drain FC2 adds
        if (t == 0) { unsigned prev; flag_bump(&g_d2, &prev); }
        return;
    }

    // ================= GCN + FC1 role (blocks 0..20) =================
    __shared__ float sA[21 * APAD];
    __shared__ float sX[21 * W1PAD];
    __shared__ float sW1T[21 * W1PAD];
    __shared__ float sW2T[21 * APAD];
    __shared__ float sT[21 * APAD];      // h1T then h2T
    __shared__ float sG[21 * APAD];      // g1
    __shared__ float sv[21];             // v row b
    __shared__ float sdeg[21];
    __shared__ float sb1[21], sb2[21];

    // P0: zero pads, stage X/W1T/W2T, edges (round-11 verbatim)
    for (int i = t; i < 21 * APAD; i += 512) {
        sA[i] = 0.0f; sW2T[i] = 0.0f; sT[i] = 0.0f; sG[i] = 0.0f;
    }
    if (t < 21) { sdeg[t] = 1.0f; sb1[t] = b1[t]; sb2[t] = b2[t]; }
    {
        const float4* src4 = (const float4*)state;      // batch 0
        for (int i = t; i < 672; i += 512) {            // 21*128/4
            int n = i >> 5, fc = i & 31;
            ((float4*)&sX[n * W1PAD])[fc] = src4[i];
        }
    }
    for (int i = t; i < 2688; i += 512) {               // W1 -> sW1T[k][f]
        int f = i / 21, k = i - f * 21;
        sW1T[k * W1PAD + f] = W1[i];
    }
    for (int i = t; i < 441; i += 512) {                // W2 -> sW2T[k][f]
        int f = i / 21, k = i - f * 21;
        sW2T[k * APAD + f] = W2[i];
    }
    int er = 0, ec = 0;
    if (t < 128) { er = edge_index[t]; ec = edge_index[128 + t]; }

    // Coalesced row-prefetch of FC1 weights rows [21b, 21b+21):
    float wf1v[21];
    #pragma unroll
    for (int i = 0; i < 21; ++i) wf1v[i] = Wf1[(size_t)(21 * b + i) * 512 + t];

    lds_barrier();

    // P1: adjacency scatter (+deg, +self-loop)  ||  h1 = X @ W1
    if (t < 128) {
        atomicAdd(&sA[er * APAD + ec], 1.0f);
        atomicAdd(&sdeg[ec], 1.0f);
    }
    if (t < 21) atomicAdd(&sA[t * APAD + t], 1.0f);
    if (t < 441) {
        int n = t / 21, k = t - n * 21;
        const float4* x4 = (const float4*)&sX[n * W1PAD];
        const float4* w4 = (const float4*)&sW1T[k * W1PAD];
        float s = 0.0f;
        #pragma unroll
        for (int fc = 0; fc < 32; ++fc) {
            float4 a = x4[fc], ww = w4[fc];
            s += a.x * ww.x; s += a.y * ww.y; s += a.z * ww.z; s += a.w * ww.w;
        }
        sT[k * APAD + n] = s;
    }
    lds_barrier();

    // P2: normalize A
    if (t < 441) {
        int r = t / 21, c = t - r * 21;
        float dr = 1.0f / sqrtf(sdeg[r]);
        float dc = 1.0f / sqrtf(sdeg[c]);
        sA[r * APAD + c] = dr * sA[r * APAD + c] * dc;
    }
    lds_barrier();

    // P3: g1[i,k] = b1[k] + A[i,:] . h1T[k,:]
    if (t < 441) {
        int r = t / 21, k = t - r * 21;
        const float4* a4 = (const float4*)&sA[r * APAD];
        const float4* h4 = (const float4*)&sT[k * APAD];
        float s = sb1[k];
        #pragma unroll
        for (int jc = 0; jc < 6; ++jc) {
            float4 a = a4[jc], h = h4[jc];
            s += a.x * h.x; s += a.y * h.y; s += a.z * h.z; s += a.w * h.w;
        }
        sG[r * APAD + k] = s;
    }
    lds_barrier();

    // P4: h2[n,k] = g1[n,:] . W2T[k,:]
    if (t < 441) {
        int n = t / 21, k = t - n * 21;
        const float4* g4 = (const float4*)&sG[n * APAD];
        const float4* w4 = (const float4*)&sW2T[k * APAD];
        float s = 0.0f;
        #pragma unroll
        for (int jc = 0; jc < 6; ++jc) {
            float4 g = g4[jc], ww = w4[jc];
            s += g.x * ww.x; s += g.y * ww.y; s += g.z * ww.z; s += g.w * ww.w;
        }
        sT[k * APAD + n] = s;
    }
    lds_barrier();

    // P5 (row b only): v[b,k] = b2[k] + A[b,:] . h2T[k,:]
    // Concurrently, an idle wave-7 lane absorbs the g_zr gate (set by block
    // 44 within ~1us of launch; poll overlaps P5, costs zero serial time).
    if (t < 21) {
        const int k = t;
        const float4* a4 = (const float4*)&sA[b * APAD];
        const float4* h4 = (const float4*)&sT[k * APAD];
        float s = sb2[k];
        #pragma unroll
        for (int jc = 0; jc < 6; ++jc) {
            float4 a = a4[jc], h = h4[jc];
            s += a.x * h.x; s += a.y * h.y; s += a.z * h.z; s += a.w * h.w;
        }
        sv[k] = s;
    }
    if (t == 448) {
        while (flag_load(&g_zr) == 0u) __builtin_amdgcn_s_sleep(1);
    }
    lds_barrier();   // orders sv writes AND the gate before FC1 adds

    // FC1 (row-split): rows [21b, 21b+21) -> acc1
    {
        float s = 0.0f;
        #pragma unroll
        for (int r = 0; r < 21; ++r) s += sv[r] * wf1v[r];
        agent_fadd(&ws[WS_ACC1 + t], s);
    }

    __syncthreads();                              // drain FC1 adds
    if (t == 0) { unsigned prev; flag_bump(&g_d1, &prev); }
}

extern "C" void kernel_launch(void* const* d_in, const int* in_sizes, int n_in,
                              void* d_out, int out_size, void* d_ws, size_t ws_size,
                              hipStream_t stream)
{
    const float* state      = (const float*)d_in[0];
    const int*   edge_index = (const int*)  d_in[1];
    const float* W1  = (const float*)d_in[2];
    const float* b1  = (const float*)d_in[3];
    const float* W2  = (const float*)d_in[4];
    const float* b2  = (const float*)d_in[5];
    const float* Wf1 = (const float*)d_in[6];
    const float* bf1 = (const float*)d_in[7];
    const float* Wf2 = (const float*)d_in[8];
    const float* bf2 = (const float*)d_in[9];
    const float* Wf3 = (const float*)d_in[10];
    const float* bf3 = (const float*)d_in[11];

    float* ws  = (float*)d_ws;
    float* out = (float*)d_out;

    fused_kernel<<<45, 512, 0, stream>>>(state, edge_index, W1, b1, W2, b2,
                                         Wf1, bf1, Wf2, bf2, Wf3, bf3, ws, out);
}